// Round 7
// baseline (508.184 us; speedup 1.0000x reference)
//
#include <hip/hip_runtime.h>

#define SEQ    512
#define DM     512
#define DI     1024
#define NH     16
#define DS     64
#define CONVD  1152
#define DPROJ  2192
#define NPADIN 2304

typedef __attribute__((ext_vector_type(8))) short bf16x8;
typedef __attribute__((ext_vector_type(4))) float floatx4;

__device__ __forceinline__ unsigned int f2bf(float f) {
  unsigned int u = __float_as_uint(f);
  u += 0x7FFFu + ((u >> 16) & 1u);   // RNE
  return u >> 16;
}
__device__ __forceinline__ ushort4 cvt4(float4 v) {
  ushort4 o;
  o.x = (unsigned short)f2bf(v.x); o.y = (unsigned short)f2bf(v.y);
  o.z = (unsigned short)f2bf(v.z); o.w = (unsigned short)f2bf(v.w);
  return o;
}
__device__ __forceinline__ float sigmoidf_(float x) { return 1.f / (1.f + __expf(-x)); }
__device__ __forceinline__ float siluf_(float x) { return x * sigmoidf_(x); }

__device__ __forceinline__ void gl16(const void* g, void* l) {
  __builtin_amdgcn_global_load_lds(
      (const __attribute__((address_space(1))) unsigned int*)g,
      (__attribute__((address_space(3))) unsigned int*)l, 16, 0, 0);
}

// ---------------------------------------------------------------------------
// bf16 C = A * B^T GEMM (round-0 best-measured config). BK=64, 128B LDS rows
// with XOR chunk swizzle applied on the per-lane GLOBAL source address
// (gl16's LDS side is forced lane-contiguous).
// EPI 0: fp32 store, guard gn < Nvalid (in_proj -> zx)
// EPI 1: v += Xf[mm][gn]; Xcat[f+b16][mm][(gm>>10)*512+gn] (out_proj)
// EPI 2: zg=sigmoid(v+bias); xn = zg*Xcatf[..gn]+(1-zg)*Xcatf[..512+gn];
//        store Xf fp32 + Xb bf16 (aggr)
// EPI 3: fp32 store v + bias (lm_head)
// ---------------------------------------------------------------------------
template<int BM, int BN, int EPI>
__global__ __launch_bounds__(256) void gemm_bf(
    const short* __restrict__ A, const short* __restrict__ B,
    float* __restrict__ C, const int K, const int Nvalid, const int ldc,
    const float* __restrict__ e0, const float* __restrict__ e1,
    unsigned short* __restrict__ o2)
{
  constexpr int FM = BM / 32, FN = BN / 32;
  constexpr int PA = BM / 32, PB = BN / 32;   // staging passes (32 rows each)
  __shared__ short As[BM * 64];
  __shared__ short Bs[BN * 64];
  const int tid = threadIdx.x, lane = tid & 63, wave = tid >> 6;
  const int m0 = blockIdx.y * BM, n0 = blockIdx.x * BN;
  const int wm = (wave >> 1) * (BM / 2), wn = (wave & 1) * (BN / 2);
  const int prow = wave * 8 + (lane >> 3);            // row within 32-row pass
  const int schk = ((lane & 7) ^ (prow & 7)) << 3;    // swizzled source chunk
  const short* agp = A + (size_t)(m0 + prow) * K + schk;
  const short* bgp = B + (size_t)(n0 + prow) * K + schk;
  short* albase = &As[wave * 8 * 64];                 // wave-uniform
  short* blbase = &Bs[wave * 8 * 64];
  const int r16 = lane & 15, quad = lane >> 4;

  floatx4 acc[FM][FN];
#pragma unroll
  for (int i = 0; i < FM; i++)
#pragma unroll
    for (int j = 0; j < FN; j++) acc[i][j] = (floatx4)0.f;

  for (int k0 = 0; k0 < K; k0 += 64) {
#pragma unroll
    for (int p = 0; p < PA; ++p)
      gl16(agp + (size_t)p * 32 * K + k0, albase + p * 32 * 64);
#pragma unroll
    for (int p = 0; p < PB; ++p)
      gl16(bgp + (size_t)p * 32 * K + k0, blbase + p * 32 * 64);
    __syncthreads();
#pragma unroll
    for (int kk = 0; kk < 2; ++kk) {
      bf16x8 afr[FM], bfr[FN];
#pragma unroll
      for (int i = 0; i < FM; i++) {
        const int row = wm + i * 16 + r16;
        afr[i] = *(const bf16x8*)&As[row * 64 + (((kk * 4 + quad) ^ (row & 7)) << 3)];
      }
#pragma unroll
      for (int j = 0; j < FN; j++) {
        const int row = wn + j * 16 + r16;
        bfr[j] = *(const bf16x8*)&Bs[row * 64 + (((kk * 4 + quad) ^ (row & 7)) << 3)];
      }
#pragma unroll
      for (int i = 0; i < FM; i++)
#pragma unroll
        for (int j = 0; j < FN; j++)
          acc[i][j] = __builtin_amdgcn_mfma_f32_16x16x32_bf16(afr[i], bfr[j], acc[i][j], 0, 0, 0);
    }
    __syncthreads();
  }

  const int er = quad << 2;
#pragma unroll
  for (int i = 0; i < FM; ++i)
#pragma unroll
    for (int j = 0; j < FN; ++j)
#pragma unroll
      for (int r = 0; r < 4; ++r) {
        const int gm = m0 + wm + i * 16 + er + r;
        const int gn = n0 + wn + j * 16 + r16;
        float v = acc[i][j][r];
        if (EPI == 0) {
          if (gn < Nvalid) C[(size_t)gm * ldc + gn] = v;
        } else if (EPI == 1) {
          const int mm = gm & 1023;
          v += e0[(size_t)mm * DM + gn];
          const size_t idx = (size_t)mm * DI + ((gm >> 10) << 9) + gn;
          C[idx] = v;
          o2[idx] = (unsigned short)f2bf(v);
        } else if (EPI == 2) {
          const float zg = sigmoidf_(v + e0[gn]);
          const float xn = zg * e1[(size_t)gm * DI + gn] +
                           (1.f - zg) * e1[(size_t)gm * DI + DM + gn];
          const size_t idx = (size_t)gm * DM + gn;
          C[idx] = xn;
          o2[idx] = (unsigned short)f2bf(xn);
        } else {
          C[(size_t)gm * ldc + gn] = v + e0[gn];
        }
      }
}

// ---------------------------------------------------------------------------
// One prep launch: embed (512 blocks) + wi convert/pad (2304) + wo/aw/lmw
// convert (4480, grid-stride).
#define WO4  262144
#define AW4  131072
#define LM4  4194304
__global__ __launch_bounds__(256) void prep_k(
    const int* __restrict__ ids, const float* __restrict__ emb,
    const float* __restrict__ wi, const float* __restrict__ wo,
    const float* __restrict__ aw, const float* __restrict__ lmw,
    float* __restrict__ Xf, unsigned short* __restrict__ Xb,
    unsigned short* __restrict__ wiB, unsigned short* __restrict__ woB,
    unsigned short* __restrict__ awB, unsigned short* __restrict__ lmwB) {
  const int blk = blockIdx.x, tid = threadIdx.x;
  if (blk < 512) {
    const int m = blk * 2 + (tid >> 7), col = tid & 127;
    const int row = ids[m];
    float4 v = ((const float4*)(emb + (size_t)row * DM))[col];
    ((float4*)(Xf + (size_t)m * DM))[col] = v;
    ((ushort4*)(Xb + (size_t)m * DM))[col] = cvt4(v);
  } else if (blk < 512 + 2304) {
    const int slot = (blk - 512) * 2 + (tid >> 7), col = tid & 127;
    const int l = slot >= 2304 ? 1 : 0;
    const int row = slot - l * 2304;
    ushort4 o; o.x = o.y = o.z = o.w = 0;
    if (row < DPROJ)
      o = cvt4(((const float4*)(wi + ((size_t)l * DPROJ + row) * DM))[col]);
    ((ushort4*)(wiB + ((size_t)l * NPADIN + row) * DM))[col] = o;
  } else {
    for (int i = (blk - 2816) * 256 + tid; i < WO4 + AW4 + LM4; i += 4480 * 256) {
      int j = i;
      const float4* s; ushort4* d;
      if (j < WO4)            { s = (const float4*)wo;  d = (ushort4*)woB; }
      else if (j < WO4 + AW4) { j -= WO4; s = (const float4*)aw;  d = (ushort4*)awB; }
      else                    { j -= WO4 + AW4; s = (const float4*)lmw; d = (ushort4*)lmwB; }
      d[j] = cvt4(s[j]);
    }
  }
}

// ---------------------------------------------------------------------------
// Merged depthwise conv (both directions, one read of zx) + fused dt/dA.
__global__ __launch_bounds__(256) void conv_k(const float* __restrict__ zx,
    const float* __restrict__ cw, const float* __restrict__ cb,
    const float* __restrict__ dtb, const float* __restrict__ alog,
    float* __restrict__ xact, float* __restrict__ dtt, float* __restrict__ dAt) {
  const int t0 = (blockIdx.x & 31) << 4;
  const int half = blockIdx.x >> 5;
  const int b = blockIdx.y;
  const float* src = zx + (size_t)b * SEQ * DPROJ + DI;
  float* d0 = xact + (size_t)b * SEQ * CONVD;
  float* d1 = xact + (size_t)(2 + b) * SEQ * CONVD;

  for (int cc = 0; cc < 3; ++cc) {
    const int ci = cc * 256 + threadIdx.x;
    if (ci >= 576) break;
    const int c = half * 576 + ci;
    const float w0 = cw[c*4+0], w1 = cw[c*4+1], w2 = cw[c*4+2], w3 = cw[c*4+3];
    const float bias = cb[c];
    float a_[22];
#pragma unroll
    for (int j = 0; j < 22; ++j) {
      const int t = t0 - 3 + j;
      a_[j] = (t >= 0 && t < SEQ) ? src[(size_t)t * DPROJ + c] : 0.f;
    }
#pragma unroll
    for (int tt = 0; tt < 16; ++tt) {
      const float f = bias + w0*a_[tt]   + w1*a_[tt+1] + w2*a_[tt+2] + w3*a_[tt+3];
      const float g = bias + w3*a_[tt+3] + w2*a_[tt+4] + w1*a_[tt+5] + w0*a_[tt+6];
      d0[(size_t)(t0+tt) * CONVD + c] = siluf_(f);
      d1[(size_t)(t0+tt) * CONVD + c] = siluf_(g);
    }
  }
  if (half == 0) {
    const int hh = threadIdx.x >> 4, tt2 = threadIdx.x & 15;
    const int t = t0 + tt2;
    const float v = zx[(size_t)(b * SEQ + t) * DPROJ + 2176 + hh] + dtb[hh];
    const float dt = (v > 15.f) ? v : log1pf(__expf(v));
    const float A = -__expf(alog[hh]);
    dtt[(b * NH + hh) * SEQ + t] = dt;
    dAt[(b * NH + hh) * SEQ + t] = __expf(dt * A);
  }
}

// ---------------------------------------------------------------------------
// SSD scan, LDS-staged, 512 blocks (2 resident blocks/CU -> cross-block
// latency hiding; r6's 256 blocks = 1/CU lockstep had zero TLP).
// Partition: dir2 x b2 x h16 x ph4 x nh2; threads pl=16 (p) x nq=16 (n pairs)
// -- exactly r5's proven-correct reduction order (2 reg + 16 LDS partials).
//  - dt/dA: preloaded once into LDS *dir-remapped* (sdt[i] = step-i value),
//    then per chunk batched into 16 registers via broadcast ds_read_b128
//    (replaces 32 per-step ds_read_b32 per wave per chunk).
//  - B/C (64 floats/step) + xv (16 floats/step) staged by async
//    global_load_lds, double-buffered, issued one chunk ahead, drained by
//    the per-chunk barrier.
//  - per-step ds ops: 1x b32 (xv) + 2x b64 (B/C pair) = 3 (was 5).
__global__ __launch_bounds__(256, 2) void scan_k(const float* __restrict__ xact,
    const float* __restrict__ dtt, const float* __restrict__ dAt,
    float* __restrict__ yn) {
  const int bid = blockIdx.x;
  const int dir = bid >> 8, b = (bid >> 7) & 1, h = (bid >> 3) & 15;
  const int ph = (bid >> 1) & 3, nh = bid & 1;
  const int tid = threadIdx.x, lane = tid & 63, wave = tid >> 6;
  const int pl = tid & 15, nq = tid >> 4;            // 16 p x 16 n-pairs
  const int nb = nq << 1;
  const float* __restrict__ src = xact + (size_t)(dir * 2 + b) * SEQ * CONVD;
  const float* __restrict__ dtp = dtt + (b * NH + h) * SEQ;
  const float* __restrict__ dap = dAt + (b * NH + h) * SEQ;
  float* __restrict__ yrow = yn + (size_t)nh * (4 * SEQ * DI)
      + (size_t)(dir * 2 + b) * SEQ * DI + h * 64 + ph * 16;

  __shared__ __align__(16) float sdt[SEQ];
  __shared__ __align__(16) float sda[SEQ];
  __shared__ __align__(16) float sBC[2][16 * 64];   // [buf][s*64 + {B:0-31,C:32-63}]
  __shared__ __align__(16) float sXV[2][16 * 16];   // [buf][s*16 + pl]
  __shared__ float yp[2][16][16][17];

  // one-time dt/dA preload, dir-remapped so step index s -> sdt[c0+s]
  {
    const int i = tid * 2;
    const int s0i = dir ? (SEQ - 1 - i) : i;
    const int s1i = dir ? (SEQ - 2 - i) : (i + 1);
    sdt[i]     = dtp[s0i];  sda[i]     = dap[s0i];
    sdt[i + 1] = dtp[s1i];  sda[i + 1] = dap[s1i];
  }

  // async chunk staging: BC by all 4 waves (4 steps each), XV by wave 0
#define SCAN_STAGE(c0n, bufi) do {                                            \
    const int sb  = wave * 4 + (lane >> 4);                                   \
    const int idx = (lane & 15) * 4;                                          \
    const int tnb = dir ? (SEQ - 1 - ((c0n) + sb)) : ((c0n) + sb);            \
    gl16(src + (size_t)tnb * CONVD + DI + nh * 32 + idx + ((idx & 32) ? 32 : 0), \
         &sBC[bufi][wave * 256]);                                             \
    if (wave == 0) {                                                          \
      const int sx  = lane >> 2;                                              \
      const int tnx = dir ? (SEQ - 1 - ((c0n) + sx)) : ((c0n) + sx);          \
      gl16(src + (size_t)tnx * CONVD + h * 64 + ph * 16 + (lane & 3) * 4,     \
           &sXV[bufi][0]);                                                    \
    }                                                                         \
  } while (0)

  SCAN_STAGE(0, 0);
  __syncthreads();

  float hs0 = 0.f, hs1 = 0.f;
  int pb = 0, buf = 0;

  for (int c0 = 0; c0 < SEQ; c0 += 16, pb ^= 1, buf ^= 1) {
    if (c0 + 16 < SEQ) SCAN_STAGE(c0 + 16, buf ^ 1);
    float dtv[16], dav[16];
#pragma unroll
    for (int k = 0; k < 4; ++k) {
      *(float4*)&dtv[k * 4] = ((const float4*)(sdt + c0))[k];
      *(float4*)&dav[k * 4] = ((const float4*)(sda + c0))[k];
    }
#pragma unroll
    for (int s = 0; s < 16; ++s) {
      const float xv = sXV[buf][s * 16 + pl];
      const float2 b2 = *(const float2*)&sBC[buf][s * 64 + nb];
      const float2 c2 = *(const float2*)&sBC[buf][s * 64 + 32 + nb];
      const float dtx = dtv[s] * xv;
      float ya;
      hs0 = hs0 * dav[s] + dtx * b2.x; ya  = hs0 * c2.x;
      hs1 = hs1 * dav[s] + dtx * b2.y; ya += hs1 * c2.y;
      yp[pb][nq][s][pl] = ya;
    }
    __syncthreads();   // drains next-chunk gl16s + publishes yp
    {
      const int rt = tid >> 4, rp = tid & 15;
      const int tn = dir ? (SEQ - 1 - (c0 + rt)) : (c0 + rt);
      float s0 = 0.f;
#pragma unroll
      for (int j = 0; j < 16; ++j) s0 += yp[pb][j][rt][rp];
      yrow[(size_t)tn * DI + rp] = s0;
    }
  }
#undef SCAN_STAGE
}

// gated = (y0+y1 + xs*D[h]) * silu(z); A2b = bf16(rmsnorm(gated) * norm_w)
__global__ __launch_bounds__(256) void p2_k(const float* __restrict__ yn,
    const float* __restrict__ xact, const float* __restrict__ zx,
    const float* __restrict__ dss, const float* __restrict__ nw,
    unsigned short* __restrict__ A2b) {
  const int m2 = blockIdx.x;
  const int e4 = threadIdx.x << 2;
  const float4 ya = *(const float4*)(yn + (size_t)m2 * DI + e4);
  const float4 yb = *(const float4*)(yn + (size_t)4 * SEQ * DI + (size_t)m2 * DI + e4);
  const float4 x4 = *(const float4*)(xact + (size_t)m2 * CONVD + e4);
  const float4 z4 = *(const float4*)(zx + (size_t)(m2 & 1023) * DPROJ + e4);
  const float d = dss[e4 >> 6];
  float4 g;
  g.x = (ya.x + yb.x + x4.x * d) * siluf_(z4.x);
  g.y = (ya.y + yb.y + x4.y * d) * siluf_(z4.y);
  g.z = (ya.z + yb.z + x4.z * d) * siluf_(z4.z);
  g.w = (ya.w + yb.w + x4.w * d) * siluf_(z4.w);
  float ss = g.x*g.x + g.y*g.y + g.z*g.z + g.w*g.w;
#pragma unroll
  for (int m = 32; m >= 1; m >>= 1) ss += __shfl_xor(ss, m);
  __shared__ float red[4];
  if ((threadIdx.x & 63) == 0) red[threadIdx.x >> 6] = ss;
  __syncthreads();
  const float tot = red[0] + red[1] + red[2] + red[3];
  const float sc = rsqrtf(tot * (1.f / 1024.f) + 1e-5f);
  const float4 w4 = *(const float4*)(nw + e4);
  float4 o;
  o.x = g.x * sc * w4.x; o.y = g.y * sc * w4.y;
  o.z = g.z * sc * w4.z; o.w = g.w * sc * w4.w;
  ((ushort4*)(A2b + (size_t)m2 * DI))[threadIdx.x] = cvt4(o);
}

__global__ __launch_bounds__(128) void fnorm_k(const float* __restrict__ X,
    const float* __restrict__ w, unsigned short* __restrict__ outb) {
  const int m = blockIdx.x;
  const int e4 = threadIdx.x << 2;
  const float4 x4 = *(const float4*)(X + (size_t)m * DM + e4);
  float ss = x4.x*x4.x + x4.y*x4.y + x4.z*x4.z + x4.w*x4.w;
#pragma unroll
  for (int mm = 32; mm >= 1; mm >>= 1) ss += __shfl_xor(ss, mm);
  __shared__ float red[2];
  if ((threadIdx.x & 63) == 0) red[threadIdx.x >> 6] = ss;
  __syncthreads();
  const float tot = red[0] + red[1];
  const float sc = rsqrtf(tot * (1.f / 512.f) + 1e-5f);
  const float4 w4 = *(const float4*)(w + e4);
  float4 o;
  o.x = x4.x * sc * w4.x; o.y = x4.y * sc * w4.y;
  o.z = x4.z * sc * w4.z; o.w = x4.w * sc * w4.w;
  ((ushort4*)(outb + (size_t)m * DM))[threadIdx.x] = cvt4(o);
}

// ---------------------------------------------------------------------------
extern "C" void kernel_launch(void* const* d_in, const int* in_sizes, int n_in,
                              void* d_out, int out_size, void* d_ws, size_t ws_size,
                              hipStream_t stream) {
  (void)in_sizes; (void)n_in; (void)out_size; (void)ws_size;
  const int*   ids  = (const int*)d_in[0];
  const float* emb  = (const float*)d_in[2];
  const float* wi   = (const float*)d_in[3];
  const float* cw   = (const float*)d_in[4];
  const float* cb   = (const float*)d_in[5];
  const float* dtb  = (const float*)d_in[6];
  const float* alog = (const float*)d_in[7];
  const float* dss  = (const float*)d_in[8];
  const float* nw   = (const float*)d_in[9];
  const float* wo   = (const float*)d_in[10];
  const float* aw   = (const float*)d_in[11];
  const float* ab   = (const float*)d_in[12];
  const float* nfw  = (const float*)d_in[13];
  const float* lmw  = (const float*)d_in[14];
  const float* lmb  = (const float*)d_in[15];
  float* out = (float*)d_out;

  float* ws    = (float*)d_ws;
  float* Xf    = ws;                                 //  524288
  float* zx    = Xf    + (size_t)524288;             // 2244608
  float* xact  = zx    + (size_t)2244608;            // 2359296
  float* dtt   = xact  + (size_t)2359296;            //   16384
  float* dAt   = dtt   + (size_t)16384;              //   16384
  float* yn    = dAt   + (size_t)16384;              // 4194304 (2 halves)
  float* Xcatf = yn    + (size_t)4194304;            // 1048576
  unsigned short* Xb    = (unsigned short*)(Xcatf + (size_t)1048576);
  unsigned short* A2b   = Xb    + (size_t)524288;
  unsigned short* Xcatb = A2b   + (size_t)2097152;
  unsigned short* hnb   = Xcatb + (size_t)1048576;
  unsigned short* wiB   = hnb   + (size_t)524288;
  unsigned short* woB   = wiB   + (size_t)2359296;
  unsigned short* awB   = woB   + (size_t)1048576;
  unsigned short* lmwB  = awB   + (size_t)524288;

  prep_k<<<dim3(7296), dim3(256), 0, stream>>>(ids, emb, wi, wo, aw, lmw,
                                               Xf, Xb, wiB, woB, awB, lmwB);

  for (int layer = 0; layer < 2; ++layer) {
    gemm_bf<128, 128, 0><<<dim3(18, 8), dim3(256), 0, stream>>>(
        (const short*)Xb, (const short*)(wiB + (size_t)layer * NPADIN * DM),
        zx, 512, 2192, 2192, nullptr, nullptr, nullptr);
    conv_k<<<dim3(64, 2), dim3(256), 0, stream>>>(
        zx, cw + (size_t)layer * 4608, cb + (size_t)layer * 1152,
        dtb + 16 * layer, alog + 16 * layer, xact, dtt, dAt);
    scan_k<<<dim3(512), dim3(256), 0, stream>>>(xact, dtt, dAt, yn);
    p2_k<<<dim3(2048), dim3(256), 0, stream>>>(yn, xact, zx, dss + 16 * layer,
                                               nw + (size_t)layer * 1024, A2b);
    gemm_bf<64, 128, 1><<<dim3(4, 32), dim3(256), 0, stream>>>(
        (const short*)A2b, (const short*)(woB + (size_t)layer * DM * DI),
        Xcatf, 1024, 512, 512, Xf, nullptr, Xcatb);
    gemm_bf<64, 64, 2><<<dim3(8, 16), dim3(256), 0, stream>>>(
        (const short*)Xcatb, (const short*)awB,
        Xf, 1024, 512, 512, ab, Xcatf, Xb);
  }
  fnorm_k<<<dim3(1024), dim3(128), 0, stream>>>(Xf, nfw, hnb);
  gemm_bf<128, 128, 3><<<dim3(256, 8), dim3(256), 0, stream>>>(
      (const short*)hnb, (const short*)lmwB, out, 512, 32768, 32768, lmb, nullptr, nullptr);
}

// Round 8
// 481.509 us; speedup vs baseline: 1.0554x; 1.0554x over previous
//
#include <hip/hip_runtime.h>

#define SEQ    512
#define DM     512
#define DI     1024
#define NH     16
#define DS     64
#define CONVD  1152
#define DPROJ  2192
#define NPADIN 2304

typedef __attribute__((ext_vector_type(8))) short bf16x8;
typedef __attribute__((ext_vector_type(4))) float floatx4;

__device__ __forceinline__ unsigned int f2bf(float f) {
  unsigned int u = __float_as_uint(f);
  u += 0x7FFFu + ((u >> 16) & 1u);   // RNE
  return u >> 16;
}
__device__ __forceinline__ ushort4 cvt4(float4 v) {
  ushort4 o;
  o.x = (unsigned short)f2bf(v.x); o.y = (unsigned short)f2bf(v.y);
  o.z = (unsigned short)f2bf(v.z); o.w = (unsigned short)f2bf(v.w);
  return o;
}
__device__ __forceinline__ float sigmoidf_(float x) { return 1.f / (1.f + __expf(-x)); }
__device__ __forceinline__ float siluf_(float x) { return x * sigmoidf_(x); }

__device__ __forceinline__ void gl16(const void* g, void* l) {
  __builtin_amdgcn_global_load_lds(
      (const __attribute__((address_space(1))) unsigned int*)g,
      (__attribute__((address_space(3))) unsigned int*)l, 16, 0, 0);
}

// ---------------------------------------------------------------------------
// bf16 C = A * B^T GEMM. BK=64, single-buffered, 128B LDS rows with XOR
// chunk swizzle applied on the per-lane GLOBAL source address (gl16's LDS
// side is forced lane-contiguous). Tile shapes chosen per call site so every
// launch has >= 1 block/CU (256+ blocks) while keeping BN=64..128 for MFMA
// density; accumulation order per output element is identical across shapes.
// EPI 0: fp32 store, guard gn < Nvalid (in_proj -> zx)
// EPI 1: v += Xf[mm][gn]; Xcat[f+b16][mm][(gm>>10)*512+gn] (out_proj)
// EPI 2: zg=sigmoid(v+bias); xn = zg*Xcatf[..gn]+(1-zg)*Xcatf[..512+gn];
//        store Xf fp32 + Xb bf16 (aggr)
// EPI 3: fp32 store v + bias (lm_head)
// ---------------------------------------------------------------------------
template<int BM, int BN, int EPI>
__global__ __launch_bounds__(256) void gemm_bf(
    const short* __restrict__ A, const short* __restrict__ B,
    float* __restrict__ C, const int K, const int Nvalid, const int ldc,
    const float* __restrict__ e0, const float* __restrict__ e1,
    unsigned short* __restrict__ o2)
{
  constexpr int FM = BM / 32, FN = BN / 32;
  constexpr int PA = BM / 32, PB = BN / 32;   // staging passes (32 rows each)
  __shared__ short As[BM * 64];
  __shared__ short Bs[BN * 64];
  const int tid = threadIdx.x, lane = tid & 63, wave = tid >> 6;
  const int m0 = blockIdx.y * BM, n0 = blockIdx.x * BN;
  const int wm = (wave >> 1) * (BM / 2), wn = (wave & 1) * (BN / 2);
  const int prow = wave * 8 + (lane >> 3);            // row within 32-row pass
  const int schk = ((lane & 7) ^ (prow & 7)) << 3;    // swizzled source chunk
  const short* agp = A + (size_t)(m0 + prow) * K + schk;
  const short* bgp = B + (size_t)(n0 + prow) * K + schk;
  short* albase = &As[wave * 512];                    // wave-uniform
  short* blbase = &Bs[wave * 512];
  const int r16 = lane & 15, quad = lane >> 4;

  floatx4 acc[FM][FN];
#pragma unroll
  for (int i = 0; i < FM; i++)
#pragma unroll
    for (int j = 0; j < FN; j++) acc[i][j] = (floatx4)0.f;

  for (int k0 = 0; k0 < K; k0 += 64) {
#pragma unroll
    for (int p = 0; p < PA; ++p)
      gl16(agp + (size_t)p * 32 * K + k0, albase + p * 2048);
#pragma unroll
    for (int p = 0; p < PB; ++p)
      gl16(bgp + (size_t)p * 32 * K + k0, blbase + p * 2048);
    __syncthreads();
#pragma unroll
    for (int kk = 0; kk < 2; ++kk) {
      bf16x8 afr[FM], bfr[FN];
#pragma unroll
      for (int i = 0; i < FM; i++) {
        const int row = wm + i * 16 + r16;
        afr[i] = *(const bf16x8*)&As[row * 64 + (((kk * 4 + quad) ^ (row & 7)) << 3)];
      }
#pragma unroll
      for (int j = 0; j < FN; j++) {
        const int row = wn + j * 16 + r16;
        bfr[j] = *(const bf16x8*)&Bs[row * 64 + (((kk * 4 + quad) ^ (row & 7)) << 3)];
      }
#pragma unroll
      for (int i = 0; i < FM; i++)
#pragma unroll
        for (int j = 0; j < FN; j++)
          acc[i][j] = __builtin_amdgcn_mfma_f32_16x16x32_bf16(afr[i], bfr[j], acc[i][j], 0, 0, 0);
    }
    __syncthreads();
  }

  const int er = quad << 2;
#pragma unroll
  for (int i = 0; i < FM; ++i)
#pragma unroll
    for (int j = 0; j < FN; ++j)
#pragma unroll
      for (int r = 0; r < 4; ++r) {
        const int gm = m0 + wm + i * 16 + er + r;
        const int gn = n0 + wn + j * 16 + r16;
        float v = acc[i][j][r];
        if (EPI == 0) {
          if (gn < Nvalid) C[(size_t)gm * ldc + gn] = v;
        } else if (EPI == 1) {
          const int mm = gm & 1023;
          v += e0[(size_t)mm * DM + gn];
          const size_t idx = (size_t)mm * DI + ((gm >> 10) << 9) + gn;
          C[idx] = v;
          o2[idx] = (unsigned short)f2bf(v);
        } else if (EPI == 2) {
          const float zg = sigmoidf_(v + e0[gn]);
          const float xn = zg * e1[(size_t)gm * DI + gn] +
                           (1.f - zg) * e1[(size_t)gm * DI + DM + gn];
          const size_t idx = (size_t)gm * DM + gn;
          C[idx] = xn;
          o2[idx] = (unsigned short)f2bf(xn);
        } else {
          C[(size_t)gm * ldc + gn] = v + e0[gn];
        }
      }
}

// ---------------------------------------------------------------------------
// One prep launch: embed (512 blocks) + wi convert/pad (2304) + wo/aw/lmw
// convert (4480, grid-stride).
#define WO4  262144
#define AW4  131072
#define LM4  4194304
__global__ __launch_bounds__(256) void prep_k(
    const int* __restrict__ ids, const float* __restrict__ emb,
    const float* __restrict__ wi, const float* __restrict__ wo,
    const float* __restrict__ aw, const float* __restrict__ lmw,
    float* __restrict__ Xf, unsigned short* __restrict__ Xb,
    unsigned short* __restrict__ wiB, unsigned short* __restrict__ woB,
    unsigned short* __restrict__ awB, unsigned short* __restrict__ lmwB) {
  const int blk = blockIdx.x, tid = threadIdx.x;
  if (blk < 512) {
    const int m = blk * 2 + (tid >> 7), col = tid & 127;
    const int row = ids[m];
    float4 v = ((const float4*)(emb + (size_t)row * DM))[col];
    ((float4*)(Xf + (size_t)m * DM))[col] = v;
    ((ushort4*)(Xb + (size_t)m * DM))[col] = cvt4(v);
  } else if (blk < 512 + 2304) {
    const int slot = (blk - 512) * 2 + (tid >> 7), col = tid & 127;
    const int l = slot >= 2304 ? 1 : 0;
    const int row = slot - l * 2304;
    ushort4 o; o.x = o.y = o.z = o.w = 0;
    if (row < DPROJ)
      o = cvt4(((const float4*)(wi + ((size_t)l * DPROJ + row) * DM))[col]);
    ((ushort4*)(wiB + ((size_t)l * NPADIN + row) * DM))[col] = o;
  } else {
    for (int i = (blk - 2816) * 256 + tid; i < WO4 + AW4 + LM4; i += 4480 * 256) {
      int j = i;
      const float4* s; ushort4* d;
      if (j < WO4)            { s = (const float4*)wo;  d = (ushort4*)woB; }
      else if (j < WO4 + AW4) { j -= WO4; s = (const float4*)aw;  d = (ushort4*)awB; }
      else                    { j -= WO4 + AW4; s = (const float4*)lmw; d = (ushort4*)lmwB; }
      d[j] = cvt4(s[j]);
    }
  }
}

// ---------------------------------------------------------------------------
// Merged depthwise conv (both directions, one read of zx) + fused dt/dA.
// 8-timestep chunks -> 256 blocks (1 block/CU; was 128 = half the chip idle).
__global__ __launch_bounds__(256) void conv_k(const float* __restrict__ zx,
    const float* __restrict__ cw, const float* __restrict__ cb,
    const float* __restrict__ dtb, const float* __restrict__ alog,
    float* __restrict__ xact, float* __restrict__ dtt, float* __restrict__ dAt) {
  const int t0 = (blockIdx.x & 63) << 3;
  const int half = blockIdx.x >> 6;
  const int b = blockIdx.y;
  const float* src = zx + (size_t)b * SEQ * DPROJ + DI;
  float* d0 = xact + (size_t)b * SEQ * CONVD;
  float* d1 = xact + (size_t)(2 + b) * SEQ * CONVD;

  for (int cc = 0; cc < 3; ++cc) {
    const int ci = cc * 256 + threadIdx.x;
    if (ci >= 576) break;
    const int c = half * 576 + ci;
    const float w0 = cw[c*4+0], w1 = cw[c*4+1], w2 = cw[c*4+2], w3 = cw[c*4+3];
    const float bias = cb[c];
    float a_[14];
#pragma unroll
    for (int j = 0; j < 14; ++j) {
      const int t = t0 - 3 + j;
      a_[j] = (t >= 0 && t < SEQ) ? src[(size_t)t * DPROJ + c] : 0.f;
    }
#pragma unroll
    for (int tt = 0; tt < 8; ++tt) {
      const float f = bias + w0*a_[tt]   + w1*a_[tt+1] + w2*a_[tt+2] + w3*a_[tt+3];
      const float g = bias + w3*a_[tt+3] + w2*a_[tt+4] + w1*a_[tt+5] + w0*a_[tt+6];
      d0[(size_t)(t0+tt) * CONVD + c] = siluf_(f);
      d1[(size_t)(t0+tt) * CONVD + c] = siluf_(g);
    }
  }
  if (half == 0 && threadIdx.x < 128) {
    const int hh = threadIdx.x >> 3, tt2 = threadIdx.x & 7;
    const int t = t0 + tt2;
    const float v = zx[(size_t)(b * SEQ + t) * DPROJ + 2176 + hh] + dtb[hh];
    const float dt = (v > 15.f) ? v : log1pf(__expf(v));
    const float A = -__expf(alog[hh]);
    dtt[(b * NH + hh) * SEQ + t] = dt;
    dAt[(b * NH + hh) * SEQ + t] = __expf(dt * A);
  }
}

// ---------------------------------------------------------------------------
// SSD scan, LDS-staged, 512 blocks (r7 structure, proven).
__global__ __launch_bounds__(256, 2) void scan_k(const float* __restrict__ xact,
    const float* __restrict__ dtt, const float* __restrict__ dAt,
    float* __restrict__ yn) {
  const int bid = blockIdx.x;
  const int dir = bid >> 8, b = (bid >> 7) & 1, h = (bid >> 3) & 15;
  const int ph = (bid >> 1) & 3, nh = bid & 1;
  const int tid = threadIdx.x, lane = tid & 63, wave = tid >> 6;
  const int pl = tid & 15, nq = tid >> 4;            // 16 p x 16 n-pairs
  const int nb = nq << 1;
  const float* __restrict__ src = xact + (size_t)(dir * 2 + b) * SEQ * CONVD;
  const float* __restrict__ dtp = dtt + (b * NH + h) * SEQ;
  const float* __restrict__ dap = dAt + (b * NH + h) * SEQ;
  float* __restrict__ yrow = yn + (size_t)nh * (4 * SEQ * DI)
      + (size_t)(dir * 2 + b) * SEQ * DI + h * 64 + ph * 16;

  __shared__ __align__(16) float sdt[SEQ];
  __shared__ __align__(16) float sda[SEQ];
  __shared__ __align__(16) float sBC[2][16 * 64];   // [buf][s*64 + {B:0-31,C:32-63}]
  __shared__ __align__(16) float sXV[2][16 * 16];   // [buf][s*16 + pl]
  __shared__ float yp[2][16][16][17];

  // one-time dt/dA preload, dir-remapped so step index s -> sdt[c0+s]
  {
    const int i = tid * 2;
    const int s0i = dir ? (SEQ - 1 - i) : i;
    const int s1i = dir ? (SEQ - 2 - i) : (i + 1);
    sdt[i]     = dtp[s0i];  sda[i]     = dap[s0i];
    sdt[i + 1] = dtp[s1i];  sda[i + 1] = dap[s1i];
  }

  // async chunk staging: BC by all 4 waves (4 steps each), XV by wave 0
#define SCAN_STAGE(c0n, bufi) do {                                            \
    const int sb  = wave * 4 + (lane >> 4);                                   \
    const int idx = (lane & 15) * 4;                                          \
    const int tnb = dir ? (SEQ - 1 - ((c0n) + sb)) : ((c0n) + sb);            \
    gl16(src + (size_t)tnb * CONVD + DI + nh * 32 + idx + ((idx & 32) ? 32 : 0), \
         &sBC[bufi][wave * 256]);                                             \
    if (wave == 0) {                                                          \
      const int sx  = lane >> 2;                                              \
      const int tnx = dir ? (SEQ - 1 - ((c0n) + sx)) : ((c0n) + sx);          \
      gl16(src + (size_t)tnx * CONVD + h * 64 + ph * 16 + (lane & 3) * 4,     \
           &sXV[bufi][0]);                                                    \
    }                                                                         \
  } while (0)

  SCAN_STAGE(0, 0);
  __syncthreads();

  float hs0 = 0.f, hs1 = 0.f;
  int pb = 0, buf = 0;

  for (int c0 = 0; c0 < SEQ; c0 += 16, pb ^= 1, buf ^= 1) {
    if (c0 + 16 < SEQ) SCAN_STAGE(c0 + 16, buf ^ 1);
    float dtv[16], dav[16];
#pragma unroll
    for (int k = 0; k < 4; ++k) {
      *(float4*)&dtv[k * 4] = ((const float4*)(sdt + c0))[k];
      *(float4*)&dav[k * 4] = ((const float4*)(sda + c0))[k];
    }
#pragma unroll
    for (int s = 0; s < 16; ++s) {
      const float xv = sXV[buf][s * 16 + pl];
      const float2 b2 = *(const float2*)&sBC[buf][s * 64 + nb];
      const float2 c2 = *(const float2*)&sBC[buf][s * 64 + 32 + nb];
      const float dtx = dtv[s] * xv;
      float ya;
      hs0 = hs0 * dav[s] + dtx * b2.x; ya  = hs0 * c2.x;
      hs1 = hs1 * dav[s] + dtx * b2.y; ya += hs1 * c2.y;
      yp[pb][nq][s][pl] = ya;
    }
    __syncthreads();   // drains next-chunk gl16s + publishes yp
    {
      const int rt = tid >> 4, rp = tid & 15;
      const int tn = dir ? (SEQ - 1 - (c0 + rt)) : (c0 + rt);
      float s0 = 0.f;
#pragma unroll
      for (int j = 0; j < 16; ++j) s0 += yp[pb][j][rt][rp];
      yrow[(size_t)tn * DI + rp] = s0;
    }
  }
#undef SCAN_STAGE
}

// gated = (y0+y1 + xs*D[h]) * silu(z); A2b = bf16(rmsnorm(gated) * norm_w)
__global__ __launch_bounds__(256) void p2_k(const float* __restrict__ yn,
    const float* __restrict__ xact, const float* __restrict__ zx,
    const float* __restrict__ dss, const float* __restrict__ nw,
    unsigned short* __restrict__ A2b) {
  const int m2 = blockIdx.x;
  const int e4 = threadIdx.x << 2;
  const float4 ya = *(const float4*)(yn + (size_t)m2 * DI + e4);
  const float4 yb = *(const float4*)(yn + (size_t)4 * SEQ * DI + (size_t)m2 * DI + e4);
  const float4 x4 = *(const float4*)(xact + (size_t)m2 * CONVD + e4);
  const float4 z4 = *(const float4*)(zx + (size_t)(m2 & 1023) * DPROJ + e4);
  const float d = dss[e4 >> 6];
  float4 g;
  g.x = (ya.x + yb.x + x4.x * d) * siluf_(z4.x);
  g.y = (ya.y + yb.y + x4.y * d) * siluf_(z4.y);
  g.z = (ya.z + yb.z + x4.z * d) * siluf_(z4.z);
  g.w = (ya.w + yb.w + x4.w * d) * siluf_(z4.w);
  float ss = g.x*g.x + g.y*g.y + g.z*g.z + g.w*g.w;
#pragma unroll
  for (int m = 32; m >= 1; m >>= 1) ss += __shfl_xor(ss, m);
  __shared__ float red[4];
  if ((threadIdx.x & 63) == 0) red[threadIdx.x >> 6] = ss;
  __syncthreads();
  const float tot = red[0] + red[1] + red[2] + red[3];
  const float sc = rsqrtf(tot * (1.f / 1024.f) + 1e-5f);
  const float4 w4 = *(const float4*)(nw + e4);
  float4 o;
  o.x = g.x * sc * w4.x; o.y = g.y * sc * w4.y;
  o.z = g.z * sc * w4.z; o.w = g.w * sc * w4.w;
  ((ushort4*)(A2b + (size_t)m2 * DI))[threadIdx.x] = cvt4(o);
}

__global__ __launch_bounds__(128) void fnorm_k(const float* __restrict__ X,
    const float* __restrict__ w, unsigned short* __restrict__ outb) {
  const int m = blockIdx.x;
  const int e4 = threadIdx.x << 2;
  const float4 x4 = *(const float4*)(X + (size_t)m * DM + e4);
  float ss = x4.x*x4.x + x4.y*x4.y + x4.z*x4.z + x4.w*x4.w;
#pragma unroll
  for (int mm = 32; mm >= 1; mm >>= 1) ss += __shfl_xor(ss, mm);
  __shared__ float red[2];
  if ((threadIdx.x & 63) == 0) red[threadIdx.x >> 6] = ss;
  __syncthreads();
  const float tot = red[0] + red[1];
  const float sc = rsqrtf(tot * (1.f / 512.f) + 1e-5f);
  const float4 w4 = *(const float4*)(w + e4);
  float4 o;
  o.x = x4.x * sc * w4.x; o.y = x4.y * sc * w4.y;
  o.z = x4.z * sc * w4.z; o.w = x4.w * sc * w4.w;
  ((ushort4*)(outb + (size_t)m * DM))[threadIdx.x] = cvt4(o);
}

// ---------------------------------------------------------------------------
extern "C" void kernel_launch(void* const* d_in, const int* in_sizes, int n_in,
                              void* d_out, int out_size, void* d_ws, size_t ws_size,
                              hipStream_t stream) {
  (void)in_sizes; (void)n_in; (void)out_size; (void)ws_size;
  const int*   ids  = (const int*)d_in[0];
  const float* emb  = (const float*)d_in[2];
  const float* wi   = (const float*)d_in[3];
  const float* cw   = (const float*)d_in[4];
  const float* cb   = (const float*)d_in[5];
  const float* dtb  = (const float*)d_in[6];
  const float* alog = (const float*)d_in[7];
  const float* dss  = (const float*)d_in[8];
  const float* nw   = (const float*)d_in[9];
  const float* wo   = (const float*)d_in[10];
  const float* aw   = (const float*)d_in[11];
  const float* ab   = (const float*)d_in[12];
  const float* nfw  = (const float*)d_in[13];
  const float* lmw  = (const float*)d_in[14];
  const float* lmb  = (const float*)d_in[15];
  float* out = (float*)d_out;

  float* ws    = (float*)d_ws;
  float* Xf    = ws;                                 //  524288
  float* zx    = Xf    + (size_t)524288;             // 2244608
  float* xact  = zx    + (size_t)2244608;            // 2359296
  float* dtt   = xact  + (size_t)2359296;            //   16384
  float* dAt   = dtt   + (size_t)16384;              //   16384
  float* yn    = dAt   + (size_t)16384;              // 4194304 (2 halves)
  float* Xcatf = yn    + (size_t)4194304;            // 1048576
  unsigned short* Xb    = (unsigned short*)(Xcatf + (size_t)1048576);
  unsigned short* A2b   = Xb    + (size_t)524288;
  unsigned short* Xcatb = A2b   + (size_t)2097152;
  unsigned short* hnb   = Xcatb + (size_t)1048576;
  unsigned short* wiB   = hnb   + (size_t)524288;
  unsigned short* woB   = wiB   + (size_t)2359296;
  unsigned short* awB   = woB   + (size_t)1048576;
  unsigned short* lmwB  = awB   + (size_t)524288;

  prep_k<<<dim3(7296), dim3(256), 0, stream>>>(ids, emb, wi, wo, aw, lmw,
                                               Xf, Xb, wiB, woB, awB, lmwB);

  for (int layer = 0; layer < 2; ++layer) {
    gemm_bf<64, 128, 0><<<dim3(18, 16), dim3(256), 0, stream>>>(
        (const short*)Xb, (const short*)(wiB + (size_t)layer * NPADIN * DM),
        zx, 512, 2192, 2192, nullptr, nullptr, nullptr);
    conv_k<<<dim3(128, 2), dim3(256), 0, stream>>>(
        zx, cw + (size_t)layer * 4608, cb + (size_t)layer * 1152,
        dtb + 16 * layer, alog + 16 * layer, xact, dtt, dAt);
    scan_k<<<dim3(512), dim3(256), 0, stream>>>(xact, dtt, dAt, yn);
    p2_k<<<dim3(2048), dim3(256), 0, stream>>>(yn, xact, zx, dss + 16 * layer,
                                               nw + (size_t)layer * 1024, A2b);
    gemm_bf<32, 128, 1><<<dim3(4, 64), dim3(256), 0, stream>>>(
        (const short*)A2b, (const short*)(woB + (size_t)layer * DM * DI),
        Xcatf, 1024, 512, 512, Xf, nullptr, Xcatb);
    gemm_bf<32, 64, 2><<<dim3(8, 32), dim3(256), 0, stream>>>(
        (const short*)Xcatb, (const short*)awB,
        Xf, 1024, 512, 512, ab, Xcatf, Xb);
  }
  fnorm_k<<<dim3(1024), dim3(128), 0, stream>>>(Xf, nfw, hnb);
  gemm_bf<128, 128, 3><<<dim3(256, 8), dim3(256), 0, stream>>>(
      (const short*)hnb, (const short*)lmwB, out, 512, 32768, 32768, lmb, nullptr, nullptr);
}